// Round 12
// baseline (641.045 us; speedup 1.0000x reference)
//
#include <hip/hip_runtime.h>
#include <hip/hip_fp16.h>

// GCN: 100K nodes, 1.6M edges, 128 -> 128 -> 128 -> 64 (fp32 in/out)
// v12 = v11 (XCD-sliced aggregation) completed:
//  - col[] gather-index loads are NON-TEMPORAL (v11 lesson: the 6.8MB col
//    stream + slice = 10MB > 4MB L2 -> LRU evicted the slice; FETCH 213MB).
//  - ALL intermediate tensors slice-major [8][NN][F_in/8 halves]: agg
//    blocks write full 128B lines inside their own slice region (v11's
//    row-major h had 4 XCDs co-owning each line -> WRITE 50MB vs 25.6).
//  - GEMM A-reads adapted: each 16B fragment lies inside one slice.
//  - nt stores use clang ext-vector f32x4 (HIP float4 class rejected by
//    __builtin_nontemporal_store -- v12a compile fix).
// Prep = v8 (proven). If FETCH stays >=180MB the slicing path is dead.

#define NN 100000
#define NE 1600000
#define TT (NE + NN)              // edges + self loops
#define BSH 9                      // bucket = dst >> 9 (512 nodes/bucket)
#define NBUCK ((NN + 511) / 512)   // 196
#define EPB1 8192                  // edges per partition block
#define NPB1 ((TT + EPB1 - 1) / EPB1)   // 208
#define SLOT 12288                 // slack per bucket (exp 8673, ~39 sigma)

typedef _Float16 f16x8 __attribute__((ext_vector_type(8)));
typedef float f32x4 __attribute__((ext_vector_type(4)));

// ------- W pre-transpose + zero gcursor + sentinels (replaces memset) -------

__global__ __launch_bounds__(256) void wt_conv_all(const float* __restrict__ W1,
                                                   const float* __restrict__ W2,
                                                   const float* __restrict__ W3,
                                                   _Float16* __restrict__ Wt1,
                                                   _Float16* __restrict__ Wt2,
                                                   _Float16* __restrict__ Wt3,
                                                   int* __restrict__ gcursor,
                                                   int* __restrict__ rowptr) {
    int idx = blockIdx.x * 256 + threadIdx.x;
    if (idx < 16384) {
        Wt1[(idx % 128) * 128 + idx / 128] = (_Float16)W1[idx];
    } else if (idx < 32768) {
        int i = idx - 16384;
        Wt2[(i % 128) * 128 + i / 128] = (_Float16)W2[i];
    } else if (idx < 40960) {
        int i = idx - 32768;
        Wt3[(i % 64) * 128 + i / 64] = (_Float16)W3[i];
    }
    if (idx < NBUCK) gcursor[idx] = 0;
    if (idx == 0) rowptr[NN] = TT;
}

// ---- single-pass partition: LDS hist -> bucket-space reserve -> scatter ----
// record = src | (dst & 511) << 17   (src < 2^17, local dst < 2^9)

__global__ __launch_bounds__(1024) void partition_p1(const int* __restrict__ ei,
                                                     int* __restrict__ gcursor,
                                                     int* __restrict__ part) {
    __shared__ int hist[NBUCK];
    const int tid = threadIdx.x;
    const int base = blockIdx.x * EPB1;
    for (int b = tid; b < NBUCK; b += 1024) hist[b] = 0;
    __syncthreads();
    for (int i = tid; i < EPB1; i += 1024) {
        int e = base + i;
        if (e >= TT) break;
        int d = (e < NE) ? ei[NE + e] : (e - NE);
        atomicAdd(&hist[d >> BSH], 1);
    }
    __syncthreads();
    for (int b = tid; b < NBUCK; b += 1024) {
        int cnt = hist[b];
        hist[b] = cnt ? atomicAdd(&gcursor[b], cnt) : 0;   // reserve run
    }
    __syncthreads();
    for (int i = tid; i < EPB1; i += 1024) {
        int e = base + i;
        if (e >= TT) break;
        int s, d;
        if (e < NE) { s = ei[e]; d = ei[NE + e]; }
        else        { s = d = e - NE; }
        int bk = d >> BSH;
        int pos = atomicAdd(&hist[bk], 1);
        part[bk * SLOT + pos] = s | ((d & 511) << 17);
    }
}

// -------- p2: per-block prefix (196-wide reduce) + bucket-local count/scan
// -> rowptr/dinv, counting sort -> col. 512 threads, one block per bucket.

__global__ __launch_bounds__(512) void partition_p2(const int* __restrict__ part,
                                                    const int* __restrict__ gcnt,
                                                    int* __restrict__ rowptr,
                                                    float* __restrict__ dinv,
                                                    int* __restrict__ col) {
    __shared__ int red[512];
    __shared__ int cnt[512];
    __shared__ int scn[512];
    __shared__ int cur[512];
    __shared__ int sbase;
    const int b = blockIdx.x;
    const int v0 = b << BSH;
    const int nv = min(512, NN - v0);
    const int tid = threadIdx.x;
    const int nrec = gcnt[b];
    const int* bp = part + (size_t)b * SLOT;

    red[tid] = (tid < b) ? gcnt[tid] : 0;
    cnt[tid] = 0;
    __syncthreads();
    for (int off = 256; off > 0; off >>= 1) {
        if (tid < off) red[tid] += red[tid + off];
        __syncthreads();
    }
    if (tid == 0) sbase = red[0];

    for (int i = tid; i < nrec; i += 512)
        atomicAdd(&cnt[((unsigned)bp[i]) >> 17], 1);
    __syncthreads();
    const int base = sbase;
    scn[tid] = cnt[tid];
    __syncthreads();
    for (int off = 1; off < 512; off <<= 1) {
        int a = (tid >= off) ? scn[tid - off] : 0;
        __syncthreads();
        scn[tid] += a;
        __syncthreads();
    }
    if (tid < nv) {
        int excl = scn[tid] - cnt[tid];
        rowptr[v0 + tid] = base + excl;
        dinv[v0 + tid] = rsqrtf((float)cnt[tid]);   // deg >= 1 (self loop)
        cur[tid] = base + excl;
    }
    __syncthreads();
    for (int i = tid; i < nrec; i += 512) {
        int r = bp[i];
        int pos = atomicAdd(&cur[((unsigned)r) >> 17], 1);
        col[pos] = r & 0x1FFFF;
    }
}

// ---------------- MFMA GEMM: Y = dinv[row] * (A @ W), slice-major I/O -------
// A: fp32 row-major [NN][128] (layer 1) or fp16 SLICE-MAJOR [8][NN][16].
// Y: SLICE-MAJOR [8][NN][F/8] fp16.

template <int F, bool AHALF>
__global__ __launch_bounds__(256) void gemm_mfma(const void* __restrict__ Ap,
                                                 const _Float16* __restrict__ Wt,
                                                 const float* __restrict__ dinv,
                                                 __half* __restrict__ Yh) {
    constexpr int NT = F / 16;
    __shared__ _Float16 Yl[64][136];

    const int tid = threadIdx.x;
    const int wave = tid >> 6;
    const int lane = tid & 63;
    const int m = lane & 15;
    const int q = lane >> 4;
    const int grow0 = blockIdx.x * 64;
    const int row = grow0 + wave * 16 + m;
    const bool rok = row < NN;

    f32x4 acc[NT];
#pragma unroll
    for (int t = 0; t < NT; t++) acc[t] = (f32x4){0.f, 0.f, 0.f, 0.f};

#pragma unroll
    for (int kt = 0; kt < 128; kt += 32) {
        const int k0 = kt + q * 8;
        union { f16x8 v; _Float16 e[8]; } au;
        if (rok) {
            if constexpr (AHALF) {
                // slice-major A: features k0..k0+7 lie in slice k0>>4
                const _Float16* Ah = (const _Float16*)Ap;
                au.v = *reinterpret_cast<const f16x8*>(
                    Ah + ((size_t)(k0 >> 4) * NN + row) * 16 + (k0 & 15));
            } else {
                const float* A = (const float*)Ap;
                float4 x0 = *reinterpret_cast<const float4*>(A + (size_t)row * 128 + k0);
                float4 x1 = *reinterpret_cast<const float4*>(A + (size_t)row * 128 + k0 + 4);
                au.e[0] = (_Float16)x0.x; au.e[1] = (_Float16)x0.y;
                au.e[2] = (_Float16)x0.z; au.e[3] = (_Float16)x0.w;
                au.e[4] = (_Float16)x1.x; au.e[5] = (_Float16)x1.y;
                au.e[6] = (_Float16)x1.z; au.e[7] = (_Float16)x1.w;
            }
        } else {
#pragma unroll
            for (int j = 0; j < 8; j++) au.e[j] = (_Float16)0.f;
        }
#pragma unroll
        for (int t = 0; t < NT; t++) {
            f16x8 bf = *reinterpret_cast<const f16x8*>(Wt + (t * 16 + m) * 128 + k0);
            acc[t] = __builtin_amdgcn_mfma_f32_16x16x32_f16(au.v, bf, acc[t], 0, 0, 0);
        }
    }
#pragma unroll
    for (int r = 0; r < 4; r++) {
        int lrow = wave * 16 + q * 4 + r;
        int gr = grow0 + lrow;
        float s = (gr < NN) ? dinv[gr] : 0.f;
#pragma unroll
        for (int t = 0; t < NT; t++)
            Yl[lrow][t * 16 + m] = (_Float16)(s * acc[t][r]);
    }
    __syncthreads();
    constexpr int CH = F / 8;          // 16B chunks per row
    constexpr int CPS = CH / 8;        // chunks per slice (2 for F=128, 1 for 64)
    constexpr int SF = F / 8;          // features per slice (16 or 8)
    for (int i = tid; i < 64 * CH; i += 256) {
        int lrow = i / CH, c = i % CH;
        int gr = grow0 + lrow;
        if (gr < NN) {
            int sl = c / CPS, w = c % CPS;
            *reinterpret_cast<f16x8*>(
                Yh + (size_t)sl * NN * SF + (size_t)gr * SF + w * 8) =
                *reinterpret_cast<const f16x8*>(&Yl[lrow][c * 8]);
        }
    }
}

// ---------------- helper ----------------

__device__ __forceinline__ void acc_add8(float* acc, float4 raw) {
    const __half2* h2 = reinterpret_cast<const __half2*>(&raw);
#pragma unroll
    for (int qq = 0; qq < 4; qq++) {
        float2 fv = __half22float2(h2[qq]);
        acc[2 * qq]     += fv.x;
        acc[2 * qq + 1] += fv.y;
    }
}

// ---- sliced aggregate, F=128: h = relu(dinv*sum + bias), slice-major -------
// slice s = blockIdx%8 (XCD-pinned); slice region 3.2MB resident in that
// XCD's L2. col loads NON-TEMPORAL (don't evict the slice). Output h is
// slice-major too: block writes full 128B lines in its own slice region.

__global__ __launch_bounds__(256) void agg_slice128(
        const __half* __restrict__ XWs,      // slice-major [8][NN][16]
        const int* __restrict__ rowptr,
        const int* __restrict__ col,
        const float* __restrict__ dinv,
        const float* __restrict__ bias,      // [128]
        __half* __restrict__ Hout) {         // slice-major [8][NN][16]
    const int s = blockIdx.x & 7;
    const int g = blockIdx.x >> 3;
    const int tid = threadIdx.x;
    const int lnode = tid >> 1;
    const int half = tid & 1;
    const int v = g * 128 + lnode;
    if (v >= NN) return;
    const int beg = rowptr[v];
    const int end = rowptr[v + 1];
    const float4* sbase = reinterpret_cast<const float4*>(XWs + (size_t)s * NN * 16);
    float acc[8] = {0.f, 0.f, 0.f, 0.f, 0.f, 0.f, 0.f, 0.f};
#pragma unroll 4
    for (int e = beg; e < end; e++) {
        int u = __builtin_nontemporal_load(&col[e]);
        float4 raw = sbase[u * 2 + half];
        acc_add8(acc, raw);
    }
    const float dv = dinv[v];
    union { f16x8 v8; _Float16 e8[8]; } hu;
#pragma unroll
    for (int qq = 0; qq < 8; qq++) {
        float r = dv * acc[qq] + bias[s * 16 + half * 8 + qq];
        hu.e8[qq] = (_Float16)fmaxf(r, 0.f);
    }
    __builtin_nontemporal_store(hu.v8,
        reinterpret_cast<f16x8*>(Hout + ((size_t)s * NN + v) * 16 + half * 8));
}

// ---- sliced final aggregate, F=64: out = dinv*sum + bias, fp32, no relu ----
// slice s = blockIdx%8; slice region 1.6MB. col non-temporal. out is the
// problem's row-major fp32 buffer (nt ext-vector stores).

__global__ __launch_bounds__(256) void agg_final_slice(
        const __half* __restrict__ XWs,      // slice-major [8][NN][8]
        const int* __restrict__ rowptr,
        const int* __restrict__ col,
        const float* __restrict__ dinv,
        const float* __restrict__ bias,      // [64]
        float* __restrict__ out) {
    const int s = blockIdx.x & 7;
    const int g = blockIdx.x >> 3;
    const int v = g * 256 + threadIdx.x;
    if (v >= NN) return;
    const int beg = rowptr[v];
    const int end = rowptr[v + 1];
    const float4* sbase = reinterpret_cast<const float4*>(XWs + (size_t)s * NN * 8);
    float acc[8] = {0.f, 0.f, 0.f, 0.f, 0.f, 0.f, 0.f, 0.f};
#pragma unroll 4
    for (int e = beg; e < end; e++) {
        int u = __builtin_nontemporal_load(&col[e]);
        float4 raw = sbase[u];
        acc_add8(acc, raw);
    }
    const float dv = dinv[v];
    f32x4 r0, r1;
    r0[0] = dv * acc[0] + bias[s * 8 + 0];
    r0[1] = dv * acc[1] + bias[s * 8 + 1];
    r0[2] = dv * acc[2] + bias[s * 8 + 2];
    r0[3] = dv * acc[3] + bias[s * 8 + 3];
    r1[0] = dv * acc[4] + bias[s * 8 + 4];
    r1[1] = dv * acc[5] + bias[s * 8 + 5];
    r1[2] = dv * acc[6] + bias[s * 8 + 6];
    r1[3] = dv * acc[7] + bias[s * 8 + 7];
    float* op = out + (size_t)v * 64 + s * 8;
    __builtin_nontemporal_store(r0, reinterpret_cast<f32x4*>(op));
    __builtin_nontemporal_store(r1, reinterpret_cast<f32x4*>(op + 4));
}

// ---------------- launch ----------------

extern "C" void kernel_launch(void* const* d_in, const int* in_sizes, int n_in,
                              void* d_out, int out_size, void* d_ws, size_t ws_size,
                              hipStream_t stream) {
    const float* x  = (const float*)d_in[0];
    const int*   ei = (const int*)d_in[1];
    const float* W1 = (const float*)d_in[2];
    const float* b1 = (const float*)d_in[3];
    const float* W2 = (const float*)d_in[4];
    const float* b2 = (const float*)d_in[5];
    const float* W3 = (const float*)d_in[6];
    const float* b3 = (const float*)d_in[7];
    float* out = (float*)d_out;

    char* p = (char*)d_ws;
    int*      rowptr  = (int*)p;       p += 400016;
    float*    dinv    = (float*)p;     p += 400000;
    int*      gcursor = (int*)p;       p += 1024;
    _Float16* Wt1     = (_Float16*)p;  p += 32768;
    _Float16* Wt2     = (_Float16*)p;  p += 32768;
    _Float16* Wt3     = (_Float16*)p;  p += 16384;
    int*      part    = (int*)p;       p += (size_t)NBUCK * SLOT * 4; // 9.6 MB
    int*      col     = (int*)p;       p += (size_t)TT * 4;           // 6.8 MB
    __half*   bufA    = (__half*)p;    p += (size_t)NN * 128 * 2;     // 25.6 MB
    __half*   bufB    = (__half*)p;                                    // 25.6 MB

    wt_conv_all<<<160, 256, 0, stream>>>(W1, W2, W3, Wt1, Wt2, Wt3,
                                         gcursor, rowptr);
    partition_p1<<<NPB1, 1024, 0, stream>>>(ei, gcursor, part);
    partition_p2<<<NBUCK, 512, 0, stream>>>(part, gcursor, rowptr, dinv, col);

    const int gb = (NN + 63) / 64;              // 1563
    const int ga128 = ((NN + 127) / 128) * 8;   // 6256
    const int gaf   = ((NN + 255) / 256) * 8;   // 3128

    // layer 1: xw1 = dinv * (x @ W1)   (slice-major bufA)
    gemm_mfma<128, false><<<gb, 256, 0, stream>>>(x, Wt1, dinv, bufA);
    // h1 = relu(dinv*agg(xw1) + b1)    (slice-major bufB)
    agg_slice128<<<ga128, 256, 0, stream>>>(bufA, rowptr, col, dinv, b1, bufB);
    // xw2 = dinv * (h1 @ W2)           (slice-major bufA)
    gemm_mfma<128, true><<<gb, 256, 0, stream>>>(bufB, Wt2, dinv, bufA);
    // h2 = relu(dinv*agg(xw2) + b2)    (slice-major bufB)
    agg_slice128<<<ga128, 256, 0, stream>>>(bufA, rowptr, col, dinv, b2, bufB);
    // xw3 = dinv * (h2 @ W3)           (slice-major [8][NN][8] bufA)
    gemm_mfma<64, true><<<gb, 256, 0, stream>>>(bufB, Wt3, dinv, bufA);
    // out = dinv*agg(xw3) + b3
    agg_final_slice<<<gaf, 256, 0, stream>>>(bufA, rowptr, col, dinv, b3, out);
}

// Round 13
// 518.064 us; speedup vs baseline: 1.2374x; 1.2374x over previous
//
#include <hip/hip_runtime.h>
#include <hip/hip_fp16.h>

// GCN: 100K nodes, 1.6M edges, 128 -> 128 -> 128 -> 64 (fp32 in/out)
// v13 = v12 (XCD-sliced, slice-major, nt col) + LDS-STAGED col:
// v12 counters: FETCH 213->146MB, WRITE 50->26MB (traffic theory CONFIRMED)
// but dur 113->142us: per-edge nt col load = ~900cy HBM access on the
// gather's critical path (uncoalesced 4B/thread, ~2x sector amp).
// Fix: a block's nodes own a CONTIGUOUS col range (CSR); bulk-stage it
// into LDS with coalesced nt loads (one amortized phase), gather reads
// indices from LDS. col still never enters L2 (slice stays resident),
// col traffic flat 54.4MB, no per-edge HBM latency.
// Null read: agg_slice128 >= 110us -> slicing dead, revert v8 + roofline.

#define NN 100000
#define NE 1600000
#define TT (NE + NN)              // edges + self loops
#define BSH 9                      // bucket = dst >> 9 (512 nodes/bucket)
#define NBUCK ((NN + 511) / 512)   // 196
#define EPB1 8192                  // edges per partition block
#define NPB1 ((TT + EPB1 - 1) / EPB1)   // 208
#define SLOT 12288                 // slack per bucket (exp 8673, ~39 sigma)
#define CAPA 4096                  // col cap, 128-node block (mean 2176, +42s)
#define CAPF 6144                  // col cap, 256-node block (mean 4352, +28s)

typedef _Float16 f16x8 __attribute__((ext_vector_type(8)));
typedef float f32x4 __attribute__((ext_vector_type(4)));

// ------- W pre-transpose + zero gcursor + sentinels (replaces memset) -------

__global__ __launch_bounds__(256) void wt_conv_all(const float* __restrict__ W1,
                                                   const float* __restrict__ W2,
                                                   const float* __restrict__ W3,
                                                   _Float16* __restrict__ Wt1,
                                                   _Float16* __restrict__ Wt2,
                                                   _Float16* __restrict__ Wt3,
                                                   int* __restrict__ gcursor,
                                                   int* __restrict__ rowptr) {
    int idx = blockIdx.x * 256 + threadIdx.x;
    if (idx < 16384) {
        Wt1[(idx % 128) * 128 + idx / 128] = (_Float16)W1[idx];
    } else if (idx < 32768) {
        int i = idx - 16384;
        Wt2[(i % 128) * 128 + i / 128] = (_Float16)W2[i];
    } else if (idx < 40960) {
        int i = idx - 32768;
        Wt3[(i % 64) * 128 + i / 64] = (_Float16)W3[i];
    }
    if (idx < NBUCK) gcursor[idx] = 0;
    if (idx == 0) rowptr[NN] = TT;
}

// ---- single-pass partition: LDS hist -> bucket-space reserve -> scatter ----
// record = src | (dst & 511) << 17   (src < 2^17, local dst < 2^9)

__global__ __launch_bounds__(1024) void partition_p1(const int* __restrict__ ei,
                                                     int* __restrict__ gcursor,
                                                     int* __restrict__ part) {
    __shared__ int hist[NBUCK];
    const int tid = threadIdx.x;
    const int base = blockIdx.x * EPB1;
    for (int b = tid; b < NBUCK; b += 1024) hist[b] = 0;
    __syncthreads();
    for (int i = tid; i < EPB1; i += 1024) {
        int e = base + i;
        if (e >= TT) break;
        int d = (e < NE) ? ei[NE + e] : (e - NE);
        atomicAdd(&hist[d >> BSH], 1);
    }
    __syncthreads();
    for (int b = tid; b < NBUCK; b += 1024) {
        int cnt = hist[b];
        hist[b] = cnt ? atomicAdd(&gcursor[b], cnt) : 0;   // reserve run
    }
    __syncthreads();
    for (int i = tid; i < EPB1; i += 1024) {
        int e = base + i;
        if (e >= TT) break;
        int s, d;
        if (e < NE) { s = ei[e]; d = ei[NE + e]; }
        else        { s = d = e - NE; }
        int bk = d >> BSH;
        int pos = atomicAdd(&hist[bk], 1);
        part[bk * SLOT + pos] = s | ((d & 511) << 17);
    }
}

// -------- p2: per-block prefix (196-wide reduce) + bucket-local count/scan
// -> rowptr/dinv, counting sort -> col. 512 threads, one block per bucket.

__global__ __launch_bounds__(512) void partition_p2(const int* __restrict__ part,
                                                    const int* __restrict__ gcnt,
                                                    int* __restrict__ rowptr,
                                                    float* __restrict__ dinv,
                                                    int* __restrict__ col) {
    __shared__ int red[512];
    __shared__ int cnt[512];
    __shared__ int scn[512];
    __shared__ int cur[512];
    __shared__ int sbase;
    const int b = blockIdx.x;
    const int v0 = b << BSH;
    const int nv = min(512, NN - v0);
    const int tid = threadIdx.x;
    const int nrec = gcnt[b];
    const int* bp = part + (size_t)b * SLOT;

    red[tid] = (tid < b) ? gcnt[tid] : 0;
    cnt[tid] = 0;
    __syncthreads();
    for (int off = 256; off > 0; off >>= 1) {
        if (tid < off) red[tid] += red[tid + off];
        __syncthreads();
    }
    if (tid == 0) sbase = red[0];

    for (int i = tid; i < nrec; i += 512)
        atomicAdd(&cnt[((unsigned)bp[i]) >> 17], 1);
    __syncthreads();
    const int base = sbase;
    scn[tid] = cnt[tid];
    __syncthreads();
    for (int off = 1; off < 512; off <<= 1) {
        int a = (tid >= off) ? scn[tid - off] : 0;
        __syncthreads();
        scn[tid] += a;
        __syncthreads();
    }
    if (tid < nv) {
        int excl = scn[tid] - cnt[tid];
        rowptr[v0 + tid] = base + excl;
        dinv[v0 + tid] = rsqrtf((float)cnt[tid]);   // deg >= 1 (self loop)
        cur[tid] = base + excl;
    }
    __syncthreads();
    for (int i = tid; i < nrec; i += 512) {
        int r = bp[i];
        int pos = atomicAdd(&cur[((unsigned)r) >> 17], 1);
        col[pos] = r & 0x1FFFF;
    }
}

// ---------------- MFMA GEMM: Y = dinv[row] * (A @ W), slice-major I/O -------
// A: fp32 row-major [NN][128] (layer 1) or fp16 SLICE-MAJOR [8][NN][16].
// Y: SLICE-MAJOR [8][NN][F/8] fp16.

template <int F, bool AHALF>
__global__ __launch_bounds__(256) void gemm_mfma(const void* __restrict__ Ap,
                                                 const _Float16* __restrict__ Wt,
                                                 const float* __restrict__ dinv,
                                                 __half* __restrict__ Yh) {
    constexpr int NT = F / 16;
    __shared__ _Float16 Yl[64][136];

    const int tid = threadIdx.x;
    const int wave = tid >> 6;
    const int lane = tid & 63;
    const int m = lane & 15;
    const int q = lane >> 4;
    const int grow0 = blockIdx.x * 64;
    const int row = grow0 + wave * 16 + m;
    const bool rok = row < NN;

    f32x4 acc[NT];
#pragma unroll
    for (int t = 0; t < NT; t++) acc[t] = (f32x4){0.f, 0.f, 0.f, 0.f};

#pragma unroll
    for (int kt = 0; kt < 128; kt += 32) {
        const int k0 = kt + q * 8;
        union { f16x8 v; _Float16 e[8]; } au;
        if (rok) {
            if constexpr (AHALF) {
                // slice-major A: features k0..k0+7 lie in slice k0>>4
                const _Float16* Ah = (const _Float16*)Ap;
                au.v = *reinterpret_cast<const f16x8*>(
                    Ah + ((size_t)(k0 >> 4) * NN + row) * 16 + (k0 & 15));
            } else {
                const float* A = (const float*)Ap;
                float4 x0 = *reinterpret_cast<const float4*>(A + (size_t)row * 128 + k0);
                float4 x1 = *reinterpret_cast<const float4*>(A + (size_t)row * 128 + k0 + 4);
                au.e[0] = (_Float16)x0.x; au.e[1] = (_Float16)x0.y;
                au.e[2] = (_Float16)x0.z; au.e[3] = (_Float16)x0.w;
                au.e[4] = (_Float16)x1.x; au.e[5] = (_Float16)x1.y;
                au.e[6] = (_Float16)x1.z; au.e[7] = (_Float16)x1.w;
            }
        } else {
#pragma unroll
            for (int j = 0; j < 8; j++) au.e[j] = (_Float16)0.f;
        }
#pragma unroll
        for (int t = 0; t < NT; t++) {
            f16x8 bf = *reinterpret_cast<const f16x8*>(Wt + (t * 16 + m) * 128 + k0);
            acc[t] = __builtin_amdgcn_mfma_f32_16x16x32_f16(au.v, bf, acc[t], 0, 0, 0);
        }
    }
#pragma unroll
    for (int r = 0; r < 4; r++) {
        int lrow = wave * 16 + q * 4 + r;
        int gr = grow0 + lrow;
        float s = (gr < NN) ? dinv[gr] : 0.f;
#pragma unroll
        for (int t = 0; t < NT; t++)
            Yl[lrow][t * 16 + m] = (_Float16)(s * acc[t][r]);
    }
    __syncthreads();
    constexpr int CH = F / 8;          // 16B chunks per row
    constexpr int CPS = CH / 8;        // chunks per slice (2 for F=128, 1 for 64)
    constexpr int SF = F / 8;          // features per slice (16 or 8)
    for (int i = tid; i < 64 * CH; i += 256) {
        int lrow = i / CH, c = i % CH;
        int gr = grow0 + lrow;
        if (gr < NN) {
            int sl = c / CPS, w = c % CPS;
            *reinterpret_cast<f16x8*>(
                Yh + (size_t)sl * NN * SF + (size_t)gr * SF + w * 8) =
                *reinterpret_cast<const f16x8*>(&Yl[lrow][c * 8]);
        }
    }
}

// ---------------- helper ----------------

__device__ __forceinline__ void acc_add8(float* acc, float4 raw) {
    const __half2* h2 = reinterpret_cast<const __half2*>(&raw);
#pragma unroll
    for (int qq = 0; qq < 4; qq++) {
        float2 fv = __half22float2(h2[qq]);
        acc[2 * qq]     += fv.x;
        acc[2 * qq + 1] += fv.y;
    }
}

// ---- sliced aggregate, F=128: h = relu(dinv*sum + bias), slice-major -------
// slice s = blockIdx%8 (XCD-pinned); slice region 3.2MB L2-resident.
// Block = 128 nodes; their col range is CONTIGUOUS -> bulk-staged into LDS
// with coalesced nt loads (col never enters L2, no per-edge HBM latency).

__global__ __launch_bounds__(256) void agg_slice128(
        const __half* __restrict__ XWs,      // slice-major [8][NN][16]
        const int* __restrict__ rowptr,
        const int* __restrict__ col,
        const float* __restrict__ dinv,
        const float* __restrict__ bias,      // [128]
        __half* __restrict__ Hout) {         // slice-major [8][NN][16]
    __shared__ int ecol[CAPA];
    const int s = blockIdx.x & 7;
    const int g = blockIdx.x >> 3;
    const int tid = threadIdx.x;
    const int v0 = g * 128;
    const int vend = min(v0 + 128, NN);
    const int ebeg = rowptr[v0];
    const int nrec = rowptr[vend] - ebeg;
    const bool fit = nrec <= CAPA;
    if (fit) {
        for (int i = tid; i < nrec; i += 256)
            ecol[i] = __builtin_nontemporal_load(&col[ebeg + i]);
    }
    __syncthreads();

    const int lnode = tid >> 1;
    const int half = tid & 1;
    const int v = v0 + lnode;
    if (v >= NN) return;
    const int beg = rowptr[v] - ebeg;
    const int end = rowptr[v + 1] - ebeg;
    const float4* sbase = reinterpret_cast<const float4*>(XWs + (size_t)s * NN * 16);
    float acc[8] = {0.f, 0.f, 0.f, 0.f, 0.f, 0.f, 0.f, 0.f};
    if (fit) {
#pragma unroll 4
        for (int e = beg; e < end; e++) {
            int u = ecol[e];
            float4 raw = sbase[u * 2 + half];
            acc_add8(acc, raw);
        }
    } else {   // statistically impossible overflow: direct cached reads
#pragma unroll 4
        for (int e = beg; e < end; e++) {
            int u = col[ebeg + e];
            float4 raw = sbase[u * 2 + half];
            acc_add8(acc, raw);
        }
    }
    const float dv = dinv[v];
    union { f16x8 v8; _Float16 e8[8]; } hu;
#pragma unroll
    for (int qq = 0; qq < 8; qq++) {
        float r = dv * acc[qq] + bias[s * 16 + half * 8 + qq];
        hu.e8[qq] = (_Float16)fmaxf(r, 0.f);
    }
    __builtin_nontemporal_store(hu.v8,
        reinterpret_cast<f16x8*>(Hout + ((size_t)s * NN + v) * 16 + half * 8));
}

// ---- sliced final aggregate, F=64: out = dinv*sum + bias, fp32, no relu ----
// slice s = blockIdx%8; slice region 1.6MB. Block = 256 nodes; col chunk
// LDS-staged (CAPF = mean+28sigma). nt ext-vector stores to row-major out.

__global__ __launch_bounds__(256) void agg_final_slice(
        const __half* __restrict__ XWs,      // slice-major [8][NN][8]
        const int* __restrict__ rowptr,
        const int* __restrict__ col,
        const float* __restrict__ dinv,
        const float* __restrict__ bias,      // [64]
        float* __restrict__ out) {
    __shared__ int ecol[CAPF];
    const int s = blockIdx.x & 7;
    const int g = blockIdx.x >> 3;
    const int tid = threadIdx.x;
    const int v0 = g * 256;
    const int vend = min(v0 + 256, NN);
    const int ebeg = rowptr[v0];
    const int nrec = rowptr[vend] - ebeg;
    const bool fit = nrec <= CAPF;
    if (fit) {
        for (int i = tid; i < nrec; i += 256)
            ecol[i] = __builtin_nontemporal_load(&col[ebeg + i]);
    }
    __syncthreads();

    const int v = v0 + tid;
    if (v >= NN) return;
    const int beg = rowptr[v] - ebeg;
    const int end = rowptr[v + 1] - ebeg;
    const float4* sbase = reinterpret_cast<const float4*>(XWs + (size_t)s * NN * 8);
    float acc[8] = {0.f, 0.f, 0.f, 0.f, 0.f, 0.f, 0.f, 0.f};
    if (fit) {
#pragma unroll 4
        for (int e = beg; e < end; e++) {
            int u = ecol[e];
            float4 raw = sbase[u];
            acc_add8(acc, raw);
        }
    } else {
#pragma unroll 4
        for (int e = beg; e < end; e++) {
            int u = col[ebeg + e];
            float4 raw = sbase[u];
            acc_add8(acc, raw);
        }
    }
    const float dv = dinv[v];
    f32x4 r0, r1;
    r0[0] = dv * acc[0] + bias[s * 8 + 0];
    r0[1] = dv * acc[1] + bias[s * 8 + 1];
    r0[2] = dv * acc[2] + bias[s * 8 + 2];
    r0[3] = dv * acc[3] + bias[s * 8 + 3];
    r1[0] = dv * acc[4] + bias[s * 8 + 4];
    r1[1] = dv * acc[5] + bias[s * 8 + 5];
    r1[2] = dv * acc[6] + bias[s * 8 + 6];
    r1[3] = dv * acc[7] + bias[s * 8 + 7];
    float* op = out + (size_t)v * 64 + s * 8;
    __builtin_nontemporal_store(r0, reinterpret_cast<f32x4*>(op));
    __builtin_nontemporal_store(r1, reinterpret_cast<f32x4*>(op + 4));
}

// ---------------- launch ----------------

extern "C" void kernel_launch(void* const* d_in, const int* in_sizes, int n_in,
                              void* d_out, int out_size, void* d_ws, size_t ws_size,
                              hipStream_t stream) {
    const float* x  = (const float*)d_in[0];
    const int*   ei = (const int*)d_in[1];
    const float* W1 = (const float*)d_in[2];
    const float* b1 = (const float*)d_in[3];
    const float* W2 = (const float*)d_in[4];
    const float* b2 = (const float*)d_in[5];
    const float* W3 = (const float*)d_in[6];
    const float* b3 = (const float*)d_in[7];
    float* out = (float*)d_out;

    char* p = (char*)d_ws;
    int*      rowptr  = (int*)p;       p += 400016;
    float*    dinv    = (float*)p;     p += 400000;
    int*      gcursor = (int*)p;       p += 1024;
    _Float16* Wt1     = (_Float16*)p;  p += 32768;
    _Float16* Wt2     = (_Float16*)p;  p += 32768;
    _Float16* Wt3     = (_Float16*)p;  p += 16384;
    int*      part    = (int*)p;       p += (size_t)NBUCK * SLOT * 4; // 9.6 MB
    int*      col     = (int*)p;       p += (size_t)TT * 4;           // 6.8 MB
    __half*   bufA    = (__half*)p;    p += (size_t)NN * 128 * 2;     // 25.6 MB
    __half*   bufB    = (__half*)p;                                    // 25.6 MB

    wt_conv_all<<<160, 256, 0, stream>>>(W1, W2, W3, Wt1, Wt2, Wt3,
                                         gcursor, rowptr);
    partition_p1<<<NPB1, 1024, 0, stream>>>(ei, gcursor, part);
    partition_p2<<<NBUCK, 512, 0, stream>>>(part, gcursor, rowptr, dinv, col);

    const int gb = (NN + 63) / 64;              // 1563
    const int ga128 = ((NN + 127) / 128) * 8;   // 6256
    const int gaf   = ((NN + 255) / 256) * 8;   // 3128

    // layer 1: xw1 = dinv * (x @ W1)   (slice-major bufA)
    gemm_mfma<128, false><<<gb, 256, 0, stream>>>(x, Wt1, dinv, bufA);
    // h1 = relu(dinv*agg(xw1) + b1)    (slice-major bufB)
    agg_slice128<<<ga128, 256, 0, stream>>>(bufA, rowptr, col, dinv, b1, bufB);
    // xw2 = dinv * (h1 @ W2)           (slice-major bufA)
    gemm_mfma<128, true><<<gb, 256, 0, stream>>>(bufB, Wt2, dinv, bufA);
    // h2 = relu(dinv*agg(xw2) + b2)    (slice-major bufB)
    agg_slice128<<<ga128, 256, 0, stream>>>(bufA, rowptr, col, dinv, b2, bufB);
    // xw3 = dinv * (h2 @ W3)           (slice-major [8][NN][8] bufA)
    gemm_mfma<64, true><<<gb, 256, 0, stream>>>(bufB, Wt3, dinv, bufA);
    // out = dinv*agg(xw3) + b3
    agg_final_slice<<<gaf, 256, 0, stream>>>(bufA, rowptr, col, dinv, b3, out);
}

// Round 14
// 397.515 us; speedup vs baseline: 1.6126x; 1.3033x over previous
//
#include <hip/hip_runtime.h>
#include <hip/hip_fp16.h>

// GCN: 100K nodes, 1.6M edges, 128 -> 128 -> 128 -> 64 (fp32 in/out)
// v14 = v8 VERBATIM (session best: 401.3us) -- final kernel.
// Session findings baked in:
//  - fused agg+GEMM (16-node/256-thr tile, serial edge loop unroll 4,
//    thread=(node,f-chunk)): best gather shape. Alternatives all lost:
//    wave-sweep (v2 -3.7->3.0TB/s), degree-sort (v4, occ 77->49),
//    per-wave MFMA (v5, 4x B-loads), mega-coop (v9, straggler serial).
//  - single-pass slack partition + folded scan (v8): prep 170->~55us.
//  - XCD-slicing (v11-13) CUT traffic 273->44MB but NOT time: the gather
//    is memory-REQUEST-bound (~3.5TB/s at 256B/edge is the random-access
//    request ceiling, largely L3-served), not byte-bound. Dead end.
// Roofline: 3 x 1.7M x 256B random row-gathers ~= 1.3GB at ~3.5TB/s
// ~= 280us hot floor + prep/GEMM ~= 400us total. At the ceiling.

#define NN 100000
#define NE 1600000
#define TT (NE + NN)              // edges + self loops
#define BSH 9                      // bucket = dst >> 9 (512 nodes/bucket)
#define NBUCK ((NN + 511) / 512)   // 196
#define EPB1 8192                  // edges per partition block
#define NPB1 ((TT + EPB1 - 1) / EPB1)   // 208
#define SLOT 12288                 // slack per bucket (exp 8673, ~39 sigma)

typedef _Float16 f16x8 __attribute__((ext_vector_type(8)));
typedef float f32x4 __attribute__((ext_vector_type(4)));

// ------- W pre-transpose + zero gcursor + sentinels (replaces memset) -------

__global__ __launch_bounds__(256) void wt_conv_all(const float* __restrict__ W1,
                                                   const float* __restrict__ W2,
                                                   const float* __restrict__ W3,
                                                   _Float16* __restrict__ Wt1,
                                                   _Float16* __restrict__ Wt2,
                                                   _Float16* __restrict__ Wt3,
                                                   int* __restrict__ gcursor,
                                                   int* __restrict__ rowptr) {
    int idx = blockIdx.x * 256 + threadIdx.x;
    if (idx < 16384) {
        Wt1[(idx % 128) * 128 + idx / 128] = (_Float16)W1[idx];
    } else if (idx < 32768) {
        int i = idx - 16384;
        Wt2[(i % 128) * 128 + i / 128] = (_Float16)W2[i];
    } else if (idx < 40960) {
        int i = idx - 32768;
        Wt3[(i % 64) * 128 + i / 64] = (_Float16)W3[i];
    }
    if (idx < NBUCK) gcursor[idx] = 0;
    if (idx == 0) rowptr[NN] = TT;
}

// ---- single-pass partition: LDS hist -> bucket-space reserve -> scatter ----
// record = src | (dst & 511) << 17   (src < 2^17, local dst < 2^9)

__global__ __launch_bounds__(1024) void partition_p1(const int* __restrict__ ei,
                                                     int* __restrict__ gcursor,
                                                     int* __restrict__ part) {
    __shared__ int hist[NBUCK];
    const int tid = threadIdx.x;
    const int base = blockIdx.x * EPB1;
    for (int b = tid; b < NBUCK; b += 1024) hist[b] = 0;
    __syncthreads();
    for (int i = tid; i < EPB1; i += 1024) {
        int e = base + i;
        if (e >= TT) break;
        int d = (e < NE) ? ei[NE + e] : (e - NE);
        atomicAdd(&hist[d >> BSH], 1);
    }
    __syncthreads();
    for (int b = tid; b < NBUCK; b += 1024) {
        int cnt = hist[b];
        hist[b] = cnt ? atomicAdd(&gcursor[b], cnt) : 0;   // reserve run
    }
    __syncthreads();
    for (int i = tid; i < EPB1; i += 1024) {
        int e = base + i;
        if (e >= TT) break;
        int s, d;
        if (e < NE) { s = ei[e]; d = ei[NE + e]; }
        else        { s = d = e - NE; }
        int bk = d >> BSH;
        int pos = atomicAdd(&hist[bk], 1);
        part[bk * SLOT + pos] = s | ((d & 511) << 17);
    }
}

// -------- p2: per-block prefix (196-wide reduce) + bucket-local count/scan
// -> rowptr/dinv, counting sort -> col. 512 threads, one block per bucket.

__global__ __launch_bounds__(512) void partition_p2(const int* __restrict__ part,
                                                    const int* __restrict__ gcnt,
                                                    int* __restrict__ rowptr,
                                                    float* __restrict__ dinv,
                                                    int* __restrict__ col) {
    __shared__ int red[512];
    __shared__ int cnt[512];
    __shared__ int scn[512];
    __shared__ int cur[512];
    __shared__ int sbase;
    const int b = blockIdx.x;
    const int v0 = b << BSH;
    const int nv = min(512, NN - v0);
    const int tid = threadIdx.x;
    const int nrec = gcnt[b];
    const int* bp = part + (size_t)b * SLOT;

    red[tid] = (tid < b) ? gcnt[tid] : 0;
    cnt[tid] = 0;
    __syncthreads();
    for (int off = 256; off > 0; off >>= 1) {
        if (tid < off) red[tid] += red[tid + off];
        __syncthreads();
    }
    if (tid == 0) sbase = red[0];

    for (int i = tid; i < nrec; i += 512)
        atomicAdd(&cnt[((unsigned)bp[i]) >> 17], 1);
    __syncthreads();
    const int base = sbase;
    scn[tid] = cnt[tid];
    __syncthreads();
    for (int off = 1; off < 512; off <<= 1) {
        int a = (tid >= off) ? scn[tid - off] : 0;
        __syncthreads();
        scn[tid] += a;
        __syncthreads();
    }
    if (tid < nv) {
        int excl = scn[tid] - cnt[tid];
        rowptr[v0 + tid] = base + excl;
        dinv[v0 + tid] = rsqrtf((float)cnt[tid]);   // deg >= 1 (self loop)
        cur[tid] = base + excl;
    }
    __syncthreads();
    for (int i = tid; i < nrec; i += 512) {
        int r = bp[i];
        int pos = atomicAdd(&cur[((unsigned)r) >> 17], 1);
        col[pos] = r & 0x1FFFF;
    }
}

// ---------------- MFMA GEMM: Yh[N x F](fp16) = dinv[row] * (A[N x 128] @ W) ----
// Only used for layer 1 (A fp32 = x). Frag layouts m89/m91-verified.

template <int F, bool AHALF>
__global__ __launch_bounds__(256) void gemm_mfma(const void* __restrict__ Ap,
                                                 const _Float16* __restrict__ Wt,
                                                 const float* __restrict__ dinv,
                                                 __half* __restrict__ Yh) {
    constexpr int NT = F / 16;
    __shared__ _Float16 Yl[64][136];

    const int tid = threadIdx.x;
    const int wave = tid >> 6;
    const int lane = tid & 63;
    const int m = lane & 15;
    const int q = lane >> 4;
    const int grow0 = blockIdx.x * 64;
    const int row = grow0 + wave * 16 + m;
    const bool rok = row < NN;

    f32x4 acc[NT];
#pragma unroll
    for (int t = 0; t < NT; t++) acc[t] = (f32x4){0.f, 0.f, 0.f, 0.f};

#pragma unroll
    for (int kt = 0; kt < 128; kt += 32) {
        const int k0 = kt + q * 8;
        union { f16x8 v; _Float16 e[8]; } au;
        if (rok) {
            if constexpr (AHALF) {
                au.v = *reinterpret_cast<const f16x8*>(
                    (const __half*)Ap + (size_t)row * 128 + k0);
            } else {
                const float* A = (const float*)Ap;
                float4 x0 = *reinterpret_cast<const float4*>(A + (size_t)row * 128 + k0);
                float4 x1 = *reinterpret_cast<const float4*>(A + (size_t)row * 128 + k0 + 4);
                au.e[0] = (_Float16)x0.x; au.e[1] = (_Float16)x0.y;
                au.e[2] = (_Float16)x0.z; au.e[3] = (_Float16)x0.w;
                au.e[4] = (_Float16)x1.x; au.e[5] = (_Float16)x1.y;
                au.e[6] = (_Float16)x1.z; au.e[7] = (_Float16)x1.w;
            }
        } else {
#pragma unroll
            for (int j = 0; j < 8; j++) au.e[j] = (_Float16)0.f;
        }
#pragma unroll
        for (int t = 0; t < NT; t++) {
            f16x8 bf = *reinterpret_cast<const f16x8*>(Wt + (t * 16 + m) * 128 + k0);
            acc[t] = __builtin_amdgcn_mfma_f32_16x16x32_f16(au.v, bf, acc[t], 0, 0, 0);
        }
    }
#pragma unroll
    for (int r = 0; r < 4; r++) {
        int lrow = wave * 16 + q * 4 + r;
        int gr = grow0 + lrow;
        float s = (gr < NN) ? dinv[gr] : 0.f;
#pragma unroll
        for (int t = 0; t < NT; t++)
            Yl[lrow][t * 16 + m] = (_Float16)(s * acc[t][r]);
    }
    __syncthreads();
    constexpr int CH = F / 8;
    for (int i = tid; i < 64 * CH; i += 256) {
        int lrow = i / CH, c = i % CH;
        int gr = grow0 + lrow;
        if (gr < NN)
            *reinterpret_cast<f16x8*>(Yh + (size_t)gr * F + c * 8) =
                *reinterpret_cast<const f16x8*>(&Yl[lrow][c * 8]);
    }
}

// ---------------- helper ----------------

__device__ __forceinline__ void acc_add8(float* acc, float4 raw) {
    const __half2* h2 = reinterpret_cast<const __half2*>(&raw);
#pragma unroll
    for (int qq = 0; qq < 4; qq++) {
        float2 fv = __half22float2(h2[qq]);
        acc[2 * qq]     += fv.x;
        acc[2 * qq + 1] += fv.y;
    }
}

// ---------------- fused aggregate + next-layer GEMM (v3, proven) -------------
// Block = 256 thr = 16 nodes. Gather: thread = (node tid/16, f-chunk
// tid%16), serial edge loop unroll 4 -> 4 independent 16B gathers in
// flight per thread. h = relu(dinv[v]*sum + bias) -> LDS. GEMM: 16x128
// @ Wt (16x16x32 MFMA), D scaled by dinv[row] (prescale for the next
// gather), coalesced f16x8 store.

template <int FOUT>
__global__ __launch_bounds__(256) void fused_agg_gemm(
        const __half* __restrict__ XWh,      // [NN][128] fp16, prescaled
        const int* __restrict__ rowptr,
        const int* __restrict__ col,
        const float* __restrict__ dinv,
        const float* __restrict__ bias,      // [128]
        const _Float16* __restrict__ Wt,     // [FOUT][128] fp16
        __half* __restrict__ Yout) {         // [NN][FOUT] fp16, prescaled
    __shared__ _Float16 Hs[16][136];
    __shared__ _Float16 Ds[16][FOUT + 8];

    const int tid = threadIdx.x;
    const int v0 = blockIdx.x * 16;

    // ---- gather phase ----
    {
        const int lnode = tid >> 4;       // 0..15
        const int f = tid & 15;           // 16B chunk
        const int v = v0 + lnode;
        const int beg = rowptr[v];
        const int end = rowptr[v + 1];
        const float4* base = reinterpret_cast<const float4*>(XWh);
        float acc[8] = {0.f, 0.f, 0.f, 0.f, 0.f, 0.f, 0.f, 0.f};
#pragma unroll 4
        for (int e = beg; e < end; e++) {
            int u = col[e];
            float4 raw = base[(size_t)u * 16 + f];
            acc_add8(acc, raw);
        }
        const float dv = dinv[v];
        union { f16x8 v8; _Float16 e8[8]; } hu;
#pragma unroll
        for (int qq = 0; qq < 8; qq++) {
            float r = dv * acc[qq] + bias[f * 8 + qq];
            hu.e8[qq] = (_Float16)fmaxf(r, 0.f);
        }
        *reinterpret_cast<f16x8*>(&Hs[lnode][f * 8]) = hu.v8;
    }
    __syncthreads();

    // ---- GEMM phase: D[16xFOUT] = dinv[row] * (Hs[16x128] @ Wt^T) ----
    constexpr int TPW = FOUT / 64;    // col tiles per wave: 2 (F=128) or 1
    const int wave = tid >> 6;
    const int lane = tid & 63;
    const int m = lane & 15;
    const int q = lane >> 4;
    f32x4 gacc[TPW];
#pragma unroll
    for (int t = 0; t < TPW; t++) gacc[t] = (f32x4){0.f, 0.f, 0.f, 0.f};
#pragma unroll
    for (int kt = 0; kt < 128; kt += 32) {
        const int k0 = kt + q * 8;
        f16x8 av = *reinterpret_cast<const f16x8*>(&Hs[m][k0]);
#pragma unroll
        for (int t = 0; t < TPW; t++) {
            const int gc = (wave * TPW + t) * 16 + m;
            f16x8 bv = *reinterpret_cast<const f16x8*>(Wt + gc * 128 + k0);
            gacc[t] = __builtin_amdgcn_mfma_f32_16x16x32_f16(av, bv, gacc[t], 0, 0, 0);
        }
    }
#pragma unroll
    for (int r = 0; r < 4; r++) {
        const int lrow = q * 4 + r;
        const float s = dinv[v0 + lrow];
#pragma unroll
        for (int t = 0; t < TPW; t++)
            Ds[lrow][(wave * TPW + t) * 16 + m] = (_Float16)(s * gacc[t][r]);
    }
    __syncthreads();
    constexpr int CH = FOUT / 8;
    for (int i2 = tid; i2 < 16 * CH; i2 += 256) {
        int lrow = i2 / CH, c = i2 % CH;
        *reinterpret_cast<f16x8*>(Yout + (size_t)(v0 + lrow) * FOUT + c * 8) =
            *reinterpret_cast<const f16x8*>(&Ds[lrow][c * 8]);
    }
}

// -------- final aggregate: F=64, fp32 out, bias, no relu (round-0 kernel) ----

__global__ __launch_bounds__(256) void agg_final(
        const __half* __restrict__ XWh,      // [NN][64] fp16, prescaled
        const int* __restrict__ rowptr,
        const int* __restrict__ col,
        const float* __restrict__ dinv,
        const float* __restrict__ bias,      // [64]
        float* __restrict__ out) {
    constexpr int TPN = 8;            // 64/8 chunks of 16B
    constexpr int NPB = 256 / TPN;    // 32 nodes/block
    const int v = blockIdx.x * NPB + threadIdx.x / TPN;
    const int f = threadIdx.x % TPN;
    const int beg = rowptr[v];
    const int end = rowptr[v + 1];
    const float4* base = reinterpret_cast<const float4*>(XWh);
    float acc[8] = {0.f, 0.f, 0.f, 0.f, 0.f, 0.f, 0.f, 0.f};
#pragma unroll 4
    for (int e = beg; e < end; e++) {
        int u = col[e];
        float4 raw = base[(size_t)u * TPN + f];
        acc_add8(acc, raw);
    }
    const float dv = dinv[v];
    float r[8];
#pragma unroll
    for (int q = 0; q < 8; q++)
        r[q] = dv * acc[q] + bias[f * 8 + q];
    float* op = out + (size_t)v * 64 + f * 8;
    *reinterpret_cast<float4*>(op)     = make_float4(r[0], r[1], r[2], r[3]);
    *reinterpret_cast<float4*>(op + 4) = make_float4(r[4], r[5], r[6], r[7]);
}

// ---------------- launch ----------------

extern "C" void kernel_launch(void* const* d_in, const int* in_sizes, int n_in,
                              void* d_out, int out_size, void* d_ws, size_t ws_size,
                              hipStream_t stream) {
    const float* x  = (const float*)d_in[0];
    const int*   ei = (const int*)d_in[1];
    const float* W1 = (const float*)d_in[2];
    const float* b1 = (const float*)d_in[3];
    const float* W2 = (const float*)d_in[4];
    const float* b2 = (const float*)d_in[5];
    const float* W3 = (const float*)d_in[6];
    const float* b3 = (const float*)d_in[7];
    float* out = (float*)d_out;

    char* p = (char*)d_ws;
    int*      rowptr  = (int*)p;       p += 400016;
    float*    dinv    = (float*)p;     p += 400000;
    int*      gcursor = (int*)p;       p += 1024;
    _Float16* Wt1     = (_Float16*)p;  p += 32768;
    _Float16* Wt2     = (_Float16*)p;  p += 32768;
    _Float16* Wt3     = (_Float16*)p;  p += 16384;
    int*      part    = (int*)p;       p += (size_t)NBUCK * SLOT * 4; // 9.6 MB
    int*      col     = (int*)p;       p += (size_t)TT * 4;           // 6.8 MB
    __half*   xwh1    = (__half*)p;    p += (size_t)NN * 128 * 2;     // 25.6 MB
    __half*   xwh2    = (__half*)p;                                    // 25.6 MB
    __half*   xwh3    = xwh1;          // layer-3 input reuses xwh1's space

    wt_conv_all<<<160, 256, 0, stream>>>(W1, W2, W3, Wt1, Wt2, Wt3,
                                         gcursor, rowptr);
    partition_p1<<<NPB1, 1024, 0, stream>>>(ei, gcursor, part);
    partition_p2<<<NBUCK, 512, 0, stream>>>(part, gcursor, rowptr, dinv, col);

    const int gb = (NN + 63) / 64;   // 1563
    const int fb = NN / 16;          // 6250 (exact)
    // layer 1 GEMM (A fp32): xwh1 = dinv * (x @ W1)
    gemm_mfma<128, false><<<gb, 256, 0, stream>>>(x, Wt1, dinv, xwh1);
    // fused: h1 = relu(dinv*agg(xwh1)+b1); xwh2 = dinv * (h1 @ W2)
    fused_agg_gemm<128><<<fb, 256, 0, stream>>>(xwh1, rowptr, col, dinv, b1,
                                                Wt2, xwh2);
    // fused: h2 = relu(dinv*agg(xwh2)+b2); xwh3 = dinv * (h2 @ W3)
    fused_agg_gemm<64><<<fb, 256, 0, stream>>>(xwh2, rowptr, col, dinv, b2,
                                               Wt3, xwh3);
    // final: out = dinv*agg(xwh3) + b3
    agg_final<<<NN / 32, 256, 0, stream>>>(xwh3, rowptr, col, dinv, b3, out);
}